// Round 1
// baseline (221.239 us; speedup 1.0000x reference)
//
#include <hip/hip_runtime.h>
#include <hip/hip_bf16.h>

typedef __bf16 bf16_t;
typedef __attribute__((ext_vector_type(8))) __bf16 bf16x8;
typedef __attribute__((ext_vector_type(4))) float f32x4;

#define DIM 2048
#define LAT 32
#define EPSF 1e-6f

__device__ __forceinline__ float gelu_f(float x) {
    return 0.5f * x * (1.0f + erff(x * 0.7071067811865475f));
}

// Pack We1 (2048x32 f32) and Wd2 (32x2048 f32) into bf16 MFMA B-fragment layout.
// B-frag for mfma_f32_16x16x32_bf16: lane l needs B[k = kgrp*8 + i][n = ntile*16 + (l&15)],
// kgrp = l>>4, i = 0..7, stored contiguously (16B per lane).
__global__ void pack_weights(const float* __restrict__ We1,
                             const float* __restrict__ Wd2,
                             bf16_t* __restrict__ We1p,
                             bf16_t* __restrict__ Wd2p) {
    int tid = blockIdx.x * 256 + threadIdx.x;  // 0..16383
    if (tid < 8192) {
        // We1p: tid == (t*2 + nt)*64 + l ; t = K-step 0..63, nt = 0..1
        int l  = tid & 63;
        int nt = (tid >> 6) & 1;
        int t  = tid >> 7;
        int kg = l >> 4, mm = l & 15;
        int k0 = t * 32 + kg * 8;
        int n  = nt * 16 + mm;
        bf16_t* dst = We1p + (size_t)tid * 8;
#pragma unroll
        for (int i = 0; i < 8; ++i)
            dst[i] = (bf16_t)We1[(size_t)(k0 + i) * LAT + n];
    } else {
        // Wd2p: id == nt*64 + l ; nt = 0..127 (K fits in one MFMA step)
        int id = tid - 8192;
        int l  = id & 63;
        int nt = id >> 6;
        int kg = l >> 4, mm = l & 15;
        int n  = nt * 16 + mm;
        bf16_t* dst = Wd2p + (size_t)id * 8;
#pragma unroll
        for (int i = 0; i < 8; ++i)
            dst[i] = (bf16_t)Wd2[(size_t)(kg * 8 + i) * DIM + n];
    }
}

__global__ __launch_bounds__(256, 2)
void fused_manifold(const float* __restrict__ z0, const float* __restrict__ z1,
                    const float* __restrict__ tp,
                    const bf16x8* __restrict__ We1p,
                    const float* __restrict__ be1,
                    const float* __restrict__ We2,
                    const float* __restrict__ be2,
                    const float* __restrict__ Wd1,
                    const float* __restrict__ bd1,
                    const bf16x8* __restrict__ Wd2p,
                    const float* __restrict__ bd2,
                    float* __restrict__ out) {
    const int tid  = threadIdx.x;
    const int wave = tid >> 6;
    const int lane = tid & 63;
    const int m16  = lane & 15;   // A row / B,D col within 16-tile
    const int kg   = lane >> 4;   // k-group (A/B) or row-group (D)
    const int waveRow = blockIdx.x * 64 + wave * 16;

    __shared__ float We2s[LAT * 33];
    __shared__ float Wd1s[LAT * 33];
    __shared__ float s0[4][16][LAT + 1];
    __shared__ float s1[4][16][LAT + 1];
    __shared__ float hm[4][16][LAT + 1];

    for (int i = tid; i < LAT * LAT; i += 256) {
        int r = i >> 5, c = i & 31;
        We2s[r * 33 + c] = We2[i];
        Wd1s[r * 33 + c] = Wd1[i];
    }

    const float tval = tp[0];

    // ---- Phase 1: S0 = z0_tile @ We1, S1 = z1_tile @ We1  (16 rows/wave, N=32, K=2048)
    f32x4 acc00 = {0.f, 0.f, 0.f, 0.f};
    f32x4 acc01 = acc00, acc10 = acc00, acc11 = acc00;
    const float* z0p = z0 + (size_t)(waveRow + m16) * DIM + kg * 8;
    const float* z1p = z1 + (size_t)(waveRow + m16) * DIM + kg * 8;

#pragma unroll 2
    for (int t = 0; t < 64; ++t) {
        f32x4 a0lo = *(const f32x4*)(z0p + t * 32);
        f32x4 a0hi = *(const f32x4*)(z0p + t * 32 + 4);
        f32x4 a1lo = *(const f32x4*)(z1p + t * 32);
        f32x4 a1hi = *(const f32x4*)(z1p + t * 32 + 4);
        bf16x8 b0 = We1p[(t * 2 + 0) * 64 + lane];
        bf16x8 b1 = We1p[(t * 2 + 1) * 64 + lane];
        bf16x8 a0, a1;
#pragma unroll
        for (int i = 0; i < 4; ++i) {
            a0[i]     = (bf16_t)a0lo[i];
            a0[i + 4] = (bf16_t)a0hi[i];
            a1[i]     = (bf16_t)a1lo[i];
            a1[i + 4] = (bf16_t)a1hi[i];
        }
        acc00 = __builtin_amdgcn_mfma_f32_16x16x32_bf16(a0, b0, acc00, 0, 0, 0);
        acc01 = __builtin_amdgcn_mfma_f32_16x16x32_bf16(a0, b1, acc01, 0, 0, 0);
        acc10 = __builtin_amdgcn_mfma_f32_16x16x32_bf16(a1, b0, acc10, 0, 0, 0);
        acc11 = __builtin_amdgcn_mfma_f32_16x16x32_bf16(a1, b1, acc11, 0, 0, 0);
    }

    // bias + exact GELU, D-layout (col = m16 / 16+m16, rows kg*4+i) -> LDS rows
    float be1a = be1[m16], be1b = be1[16 + m16];
#pragma unroll
    for (int i = 0; i < 4; ++i) {
        int m = kg * 4 + i;
        s0[wave][m][m16]      = gelu_f(acc00[i] + be1a);
        s0[wave][m][16 + m16] = gelu_f(acc01[i] + be1b);
        s1[wave][m][m16]      = gelu_f(acc10[i] + be1a);
        s1[wave][m][16 + m16] = gelu_f(acc11[i] + be1b);
    }
    __syncthreads();

    // ---- Phase 2: per-lane row = m16, j-chunk = kg*8..kg*8+7 (fp32)
    const int jb = kg * 8;
    float h0v[8], h1v[8];
#pragma unroll
    for (int j = 0; j < 8; ++j) { h0v[j] = be2[jb + j]; h1v[j] = h0v[j]; }
    for (int k = 0; k < 32; ++k) {
        float a0k = s0[wave][m16][k];
        float a1k = s1[wave][m16][k];
#pragma unroll
        for (int j = 0; j < 8; ++j) {
            float w = We2s[k * 33 + jb + j];
            h0v[j] += a0k * w;
            h1v[j] += a1k * w;
        }
    }
    // norms + dot (reduce across the 4 kg-lanes of each row: xor 16, 32)
    float ss0 = 0.f, ss1 = 0.f;
#pragma unroll
    for (int j = 0; j < 8; ++j) { ss0 += h0v[j] * h0v[j]; ss1 += h1v[j] * h1v[j]; }
    ss0 += __shfl_xor(ss0, 16); ss0 += __shfl_xor(ss0, 32);
    ss1 += __shfl_xor(ss1, 16); ss1 += __shfl_xor(ss1, 32);
    float n0 = sqrtf(ss0), n1 = sqrtf(ss1);
    float inv0 = 1.f / (n0 + EPSF), inv1 = 1.f / (n1 + EPSF);
    float dotp = 0.f;
#pragma unroll
    for (int j = 0; j < 8; ++j) dotp += (h0v[j] * inv0) * (h1v[j] * inv1);
    dotp += __shfl_xor(dotp, 16); dotp += __shfl_xor(dotp, 32);
    dotp = fminf(fmaxf(dotp, -1.f + EPSF), 1.f - EPSF);
    float theta   = acosf(dotp);
    float scale   = 0.5f * (n0 + n1);
    float inv_sin = 1.f / sinf(theta);
    // theta >= acos(1-1e-6) ~ 1.4e-3 > EPS, so reference always takes the slerp branch
    float c0 = sinf((1.f - tval) * theta) * inv_sin * scale * inv0;
    float c1 = sinf(tval * theta) * inv_sin * scale * inv1;
#pragma unroll
    for (int j = 0; j < 8; ++j)
        hm[wave][m16][jb + j] = c0 * h0v[j] + c1 * h1v[j];
    __syncthreads();

    // decode layer 1 (fp32) -> g lands exactly in A-fragment layout
    float gv[8];
#pragma unroll
    for (int j = 0; j < 8; ++j) gv[j] = bd1[jb + j];
    for (int k = 0; k < 32; ++k) {
        float hk = hm[wave][m16][k];
#pragma unroll
        for (int j = 0; j < 8; ++j)
            gv[j] += hk * Wd1s[k * 33 + jb + j];
    }
    bf16x8 afrag;
#pragma unroll
    for (int j = 0; j < 8; ++j) afrag[j] = (bf16_t)gelu_f(gv[j]);

    // ---- Phase 3: out_tile = g @ Wd2 + bd2  (16 rows/wave, N=2048, K=32)
    for (int nt = 0; nt < 128; ++nt) {
        bf16x8 bfrag = Wd2p[nt * 64 + lane];
        f32x4 c = {0.f, 0.f, 0.f, 0.f};
        c = __builtin_amdgcn_mfma_f32_16x16x32_bf16(afrag, bfrag, c, 0, 0, 0);
        int ncol = nt * 16 + m16;
        float bias = bd2[ncol];
#pragma unroll
        for (int i = 0; i < 4; ++i)
            out[(size_t)(waveRow + kg * 4 + i) * DIM + ncol] = c[i] + bias;
    }
}

extern "C" void kernel_launch(void* const* d_in, const int* in_sizes, int n_in,
                              void* d_out, int out_size, void* d_ws, size_t ws_size,
                              hipStream_t stream) {
    const float* z0  = (const float*)d_in[0];
    const float* z1  = (const float*)d_in[1];
    const float* tp  = (const float*)d_in[2];
    const float* We1 = (const float*)d_in[3];
    const float* be1 = (const float*)d_in[4];
    const float* We2 = (const float*)d_in[5];
    const float* be2 = (const float*)d_in[6];
    const float* Wd1 = (const float*)d_in[7];
    const float* bd1 = (const float*)d_in[8];
    const float* Wd2 = (const float*)d_in[9];
    const float* bd2 = (const float*)d_in[10];
    float* out = (float*)d_out;

    bf16_t* We1p = (bf16_t*)d_ws;                         // 65536 bf16 = 128 KB
    bf16_t* Wd2p = (bf16_t*)((char*)d_ws + 65536 * 2);    // 65536 bf16 = 128 KB

    hipLaunchKernelGGL(pack_weights, dim3(64), dim3(256), 0, stream,
                       We1, Wd2, We1p, Wd2p);
    hipLaunchKernelGGL(fused_manifold, dim3(512), dim3(256), 0, stream,
                       z0, z1, tp, (const bf16x8*)We1p, be1, We2, be2,
                       Wd1, bd1, (const bf16x8*)Wd2p, bd2, out);
}